// Round 8
// baseline (658.518 us; speedup 1.0000x reference)
//
#include <hip/hip_runtime.h>
#include <hip/hip_bf16.h>

#define FD 128

typedef __attribute__((ext_vector_type(8))) short bf16x8;
typedef __attribute__((ext_vector_type(4))) float f32x4;

__device__ __forceinline__ float bfu2f(unsigned short u) {
  return __uint_as_float(((unsigned int)u) << 16);
}
__device__ __forceinline__ float b2f(__hip_bfloat16 v) { return __bfloat162float(v); }
__device__ __forceinline__ unsigned int pk2(float lo, float hi) {
  return (unsigned int)__bfloat16_as_ushort(__float2bfloat16(lo)) |
         ((unsigned int)__bfloat16_as_ushort(__float2bfloat16(hi)) << 16);
}

// flag-dispatched external loads: ff=1 -> fp32, ff=0 -> bf16 ; fi=1 -> int64
__device__ __forceinline__ float ldf(const void* p, int i, int ff) {
  return ff ? ((const float*)p)[i] : b2f(((const __hip_bfloat16*)p)[i]);
}
__device__ __forceinline__ int ldi(const void* p, int i, int fi) {
  return fi ? (int)((const long long*)p)[i] : ((const int*)p)[i];
}

// ---------------- dtype detection ----------------
__global__ void detect_k(const void* x, const void* cols, int* flags) {
  __shared__ int cnt[2];
  if (threadIdx.x < 2) cnt[threadIdx.x] = 0;
  __syncthreads();
  const unsigned short* xu = (const unsigned short*)x;
  int big = 0;
  for (int i = threadIdx.x; i < 1024; i += 256) {
    int e = (xu[i] >> 7) & 0xFF;
    if (e >= 0x90) big++;
  }
  if (big) atomicAdd(&cnt[0], big);
  const int* ci = (const int*)cols;
  int zeros = 0;
  for (int i = threadIdx.x; i < 128; i += 256)
    if ((i & 1) && ci[i] == 0) zeros++;
  if (zeros) atomicAdd(&cnt[1], zeros);
  __syncthreads();
  if (threadIdx.x == 0) {
    flags[0] = (cnt[0] > 16) ? 1 : 0;
    flags[1] = (cnt[1] >= 32) ? 1 : 0;
  }
}

// ---------------- convert edge arrays to internal int32/f32 ----------------
__global__ void cvtall_k(const void* __restrict__ rows, const void* __restrict__ cols,
                         const void* __restrict__ vals, int nnz, int n,
                         int* __restrict__ r32, int* __restrict__ c32,
                         float* __restrict__ vf, const int* flags) {
  int ff = flags[0], fi = flags[1];
  int i = blockIdx.x * 256 + threadIdx.x;
  if (i >= nnz) return;
  int r = ldi(rows, i, fi);
  int c = ldi(cols, i, fi);
  if ((unsigned)r >= (unsigned)n) r = 0;
  if ((unsigned)c >= (unsigned)n) c = 0;
  r32[i] = r;
  c32[i] = c;
  vf[i] = ldf(vals, i, ff);
}

// ---------------- setup kernels (int32/f32 inputs) ----------------
__global__ void hist_k(const int* __restrict__ r, const int* __restrict__ c,
                       const float* __restrict__ v, int nnz,
                       float* u1, float* v1, int* cntT) {
  int i = blockIdx.x * 256 + threadIdx.x;
  if (i >= nnz) return;
  float vv = v[i];
  atomicAdd(&u1[r[i]], vv);
  atomicAdd(&v1[c[i]], vv);
  atomicAdd(&cntT[c[i]], 1);
}

// ---- parallel 3-pass scan ----
__global__ void scanA_k(const int* __restrict__ cnt, int n, int* bsum) {
  __shared__ int sh[256];
  int t = threadIdx.x;
  int i = blockIdx.x * 256 + t;
  sh[t] = (i < n) ? cnt[i] : 0;
  __syncthreads();
  for (int d = 128; d > 0; d >>= 1) {
    if (t < d) sh[t] += sh[t + d];
    __syncthreads();
  }
  if (t == 0) bsum[blockIdx.x] = sh[0];
}

__global__ void scanB_k(int* bsum, int nb, int* rpTail) {
  __shared__ int sh[256];
  int t = threadIdx.x;
  int v = (t < nb) ? bsum[t] : 0;
  sh[t] = v;
  __syncthreads();
  int val = v;
  for (int d = 1; d < 256; d <<= 1) {
    int add = (t >= d) ? sh[t - d] : 0;
    __syncthreads();
    val += add;
    sh[t] = val;
    __syncthreads();
  }
  if (t < nb) bsum[t] = val - v;
  if (t == 255) *rpTail = val;
}

__global__ void scanC_k(const int* __restrict__ cnt, int n, const int* __restrict__ bsum,
                        int* rp, int* cur) {
  __shared__ int sh[256];
  int t = threadIdx.x;
  int i = blockIdx.x * 256 + t;
  int v = (i < n) ? cnt[i] : 0;
  sh[t] = v;
  __syncthreads();
  int val = v;
  for (int d = 1; d < 256; d <<= 1) {
    int add = (t >= d) ? sh[t - d] : 0;
    __syncthreads();
    val += add;
    sh[t] = val;
    __syncthreads();
  }
  int ex = val - v + bsum[blockIdx.x];
  if (i < n) { rp[i] = ex; cur[i] = ex; }
}

__global__ void bsearch_k(const int* __restrict__ rows, int nnz, int n, int* rpA) {
  int i = blockIdx.x * 256 + threadIdx.x;
  if (i > n) return;
  int lo = 0, hi = nnz;
  while (lo < hi) { int mid = (lo + hi) >> 1; if (rows[mid] < i) lo = mid + 1; else hi = mid; }
  rpA[i] = lo;
}

__global__ void scatter_k(const int* __restrict__ r, const int* __restrict__ c,
                          const float* __restrict__ v, int nnz,
                          int* cur, int* tSrc, float* tVal) {
  int i = blockIdx.x * 256 + threadIdx.x;
  if (i >= nnz) return;
  int p = atomicAdd(&cur[c[i]], 1);
  if ((unsigned)p >= (unsigned)nnz) return;
  tSrc[p] = r[i];
  tVal[p] = v[i];
}

__global__ void deg2_k(const int* __restrict__ r, const int* __restrict__ c,
                       const float* __restrict__ v, int nnz,
                       const float* __restrict__ u1, const float* __restrict__ v1,
                       float* e1, float* e2, float* e3, float* e4) {
  int i = blockIdx.x * 256 + threadIdx.x;
  if (i >= nnz) return;
  int ri = r[i], ci = c[i];
  float vv = v[i];
  atomicAdd(&e1[ri], vv * v1[ci]);
  atomicAdd(&e3[ri], vv * u1[ci]);
  atomicAdd(&e2[ci], vv * u1[ri]);
  atomicAdd(&e4[ci], vv * v1[ri]);
}

__global__ void rsqrt_k(const float* __restrict__ e, float* __restrict__ s, int n) {
  int i = blockIdx.x * 256 + threadIdx.x;
  if (i >= n) return;
  float x = e[i];
  s[i] = (x > 0.f) ? rsqrtf(x) : 0.f;
}

// per-edge prescaled values: kills the dependent scale-gather in fh3
__global__ void prescale_k(const int* __restrict__ cT, const float* __restrict__ vT,
                           const int* __restrict__ cA, const float* __restrict__ vA,
                           const float* __restrict__ s1, const float* __restrict__ s2,
                           const float* __restrict__ s3, const float* __restrict__ s4,
                           float* __restrict__ vaT, float* __restrict__ vbT,
                           float* __restrict__ vaA, float* __restrict__ vbA, int nnz) {
  int i = blockIdx.x * 256 + threadIdx.x;
  if (i >= nnz) return;
  int ct = cT[i]; float vt = vT[i];
  vaT[i] = vt * s1[ct];
  vbT[i] = vt * s3[ct];
  int ca = cA[i]; float va = vA[i];
  vaA[i] = va * s2[ca];
  vbA[i] = va * s4[ca];
}

__global__ void bias_k(const void* a, const void* b, const void* c, const void* d,
                       const void* e, const void* f, float* bias, const int* flags) {
  int ff = flags[0];
  int i = threadIdx.x;
  bias[i] = 0.5f * (ldf(a, i, ff) + ldf(b, i, ff) + ldf(c, i, ff)
                  + ldf(d, i, ff) + ldf(e, i, ff) + ldf(f, i, ff));
}

__global__ void fill_k(unsigned short* o, int n) {
  int i = blockIdx.x * 256 + threadIdx.x;
  if (i < n) o[i] = 0x3E80;
}

// x -> internal bf16
__global__ void cvtx_k(const void* __restrict__ x, __hip_bfloat16* __restrict__ xb,
                       int n, const int* flags) {
  int ff = flags[0];
  int i = (blockIdx.x * 256 + threadIdx.x) * 4;
  if (i + 3 >= n) {
    for (int k = i; k < n; ++k) xb[k] = __float2bfloat16(ldf(x, k, ff));
    return;
  }
  xb[i + 0] = __float2bfloat16(ldf(x, i + 0, ff));
  xb[i + 1] = __float2bfloat16(ldf(x, i + 1, ff));
  xb[i + 2] = __float2bfloat16(ldf(x, i + 2, ff));
  xb[i + 3] = __float2bfloat16(ldf(x, i + 3, ff));
}

// W segs -> transposed bf16 Wt[n=128][K=768]
struct W6p { const void* w[6]; };
__global__ void wt_k(W6p ws, __hip_bfloat16* __restrict__ Wt, const int* flags) {
  int ff = flags[0];
  int idx = blockIdx.x * 256 + threadIdx.x;
  if (idx >= 6 * 16384) return;
  int seg = idx >> 14;
  int kn = idx & 16383;
  int k = kn >> 7, nn = kn & 127;
  Wt[(size_t)nn * 768 + seg * 128 + k] = __float2bfloat16(ldf(ws.w[seg], kn, ff));
}

// ---------------- fused first hop: wave-per-row, 4 slots, 2-edge unroll ----
// ot = M.xb ; oa uses prescaled va ; ob uses prescaled vb
__global__ __launch_bounds__(256) void fh3_k(
    const int* __restrict__ rp, const int* __restrict__ ci, const float* __restrict__ cv,
    const float* __restrict__ va, const float* __restrict__ vb,
    const unsigned int* __restrict__ xb,
    unsigned int* __restrict__ ot, unsigned int* __restrict__ oa,
    unsigned int* __restrict__ ob, int n) {
  int wave = threadIdx.x >> 6;
  int lane = threadIdx.x & 63;
  int es = lane >> 4;
  int li = lane & 15;
  int r = blockIdx.x * 4 + wave;
  if (r >= n) return;
  int s = rp[r], e = rp[r + 1];
  float t[8], a[8], b[8];
#pragma unroll
  for (int k = 0; k < 8; ++k) { t[k] = 0.f; a[k] = 0.f; b[k] = 0.f; }
  int j = s + es;
  for (; j + 4 < e; j += 8) {
    int c0 = ci[j], c1 = ci[j + 4];
    float v0 = cv[j], va0 = va[j], vb0 = vb[j];
    float v1 = cv[j + 4], va1 = va[j + 4], vb1 = vb[j + 4];
    uint4 u0 = *(const uint4*)(xb + (size_t)c0 * 64 + li * 4);
    uint4 u1 = *(const uint4*)(xb + (size_t)c1 * 64 + li * 4);
    unsigned int uu0[4] = {u0.x, u0.y, u0.z, u0.w};
    unsigned int uu1[4] = {u1.x, u1.y, u1.z, u1.w};
#pragma unroll
    for (int k = 0; k < 4; ++k) {
      float lo0 = __uint_as_float(uu0[k] << 16);
      float hi0 = __uint_as_float(uu0[k] & 0xFFFF0000u);
      float lo1 = __uint_as_float(uu1[k] << 16);
      float hi1 = __uint_as_float(uu1[k] & 0xFFFF0000u);
      t[2 * k]     = fmaf(v0, lo0, fmaf(v1, lo1, t[2 * k]));
      t[2 * k + 1] = fmaf(v0, hi0, fmaf(v1, hi1, t[2 * k + 1]));
      a[2 * k]     = fmaf(va0, lo0, fmaf(va1, lo1, a[2 * k]));
      a[2 * k + 1] = fmaf(va0, hi0, fmaf(va1, hi1, a[2 * k + 1]));
      b[2 * k]     = fmaf(vb0, lo0, fmaf(vb1, lo1, b[2 * k]));
      b[2 * k + 1] = fmaf(vb0, hi0, fmaf(vb1, hi1, b[2 * k + 1]));
    }
  }
  if (j < e) {
    int c = ci[j];
    float v = cv[j], vva = va[j], vvb = vb[j];
    uint4 u = *(const uint4*)(xb + (size_t)c * 64 + li * 4);
    unsigned int uu[4] = {u.x, u.y, u.z, u.w};
#pragma unroll
    for (int k = 0; k < 4; ++k) {
      float lo = __uint_as_float(uu[k] << 16);
      float hi = __uint_as_float(uu[k] & 0xFFFF0000u);
      t[2 * k]     = fmaf(v, lo, t[2 * k]);
      t[2 * k + 1] = fmaf(v, hi, t[2 * k + 1]);
      a[2 * k]     = fmaf(vva, lo, a[2 * k]);
      a[2 * k + 1] = fmaf(vva, hi, a[2 * k + 1]);
      b[2 * k]     = fmaf(vvb, lo, b[2 * k]);
      b[2 * k + 1] = fmaf(vvb, hi, b[2 * k + 1]);
    }
  }
#pragma unroll
  for (int k = 0; k < 8; ++k) {
    t[k] += __shfl_xor(t[k], 16); t[k] += __shfl_xor(t[k], 32);
    a[k] += __shfl_xor(a[k], 16); a[k] += __shfl_xor(a[k], 32);
    b[k] += __shfl_xor(b[k], 16); b[k] += __shfl_xor(b[k], 32);
  }
  if (es == 0) {
    size_t off = (size_t)r * 64 + li * 4;
    uint4 o;
    o.x = pk2(t[0], t[1]); o.y = pk2(t[2], t[3]);
    o.z = pk2(t[4], t[5]); o.w = pk2(t[6], t[7]);
    *(uint4*)(ot + off) = o;
    o.x = pk2(a[0], a[1]); o.y = pk2(a[2], a[3]);
    o.z = pk2(a[4], a[5]); o.w = pk2(a[6], a[7]);
    *(uint4*)(oa + off) = o;
    o.x = pk2(b[0], b[1]); o.y = pk2(b[2], b[3]);
    o.z = pk2(b[4], b[5]); o.w = pk2(b[6], b[7]);
    *(uint4*)(ob + off) = o;
  }
}

// ---------------- fused second hop: 2 sources, 2 outputs, 2-edge unroll ----
__global__ __launch_bounds__(256) void sh2_k(
    const int* __restrict__ rp, const int* __restrict__ ci, const float* __restrict__ cv,
    const unsigned int* __restrict__ ga, const unsigned int* __restrict__ gb,
    unsigned int* __restrict__ ya, unsigned int* __restrict__ yb,
    const float* __restrict__ rsa, const float* __restrict__ rsb, int n) {
  int wave = threadIdx.x >> 6;
  int lane = threadIdx.x & 63;
  int es = lane >> 4;
  int li = lane & 15;
  int r = blockIdx.x * 4 + wave;
  if (r >= n) return;
  int s = rp[r], e = rp[r + 1];
  float a[8], b[8];
#pragma unroll
  for (int k = 0; k < 8; ++k) { a[k] = 0.f; b[k] = 0.f; }
  int j = s + es;
  for (; j + 4 < e; j += 8) {
    int c0 = ci[j], c1 = ci[j + 4];
    float v0 = cv[j], v1 = cv[j + 4];
    size_t of0 = (size_t)c0 * 64 + li * 4;
    size_t of1 = (size_t)c1 * 64 + li * 4;
    uint4 u0 = *(const uint4*)(ga + of0);
    uint4 w0 = *(const uint4*)(gb + of0);
    uint4 u1 = *(const uint4*)(ga + of1);
    uint4 w1 = *(const uint4*)(gb + of1);
    unsigned int uu0[4] = {u0.x, u0.y, u0.z, u0.w};
    unsigned int ww0[4] = {w0.x, w0.y, w0.z, w0.w};
    unsigned int uu1[4] = {u1.x, u1.y, u1.z, u1.w};
    unsigned int ww1[4] = {w1.x, w1.y, w1.z, w1.w};
#pragma unroll
    for (int k = 0; k < 4; ++k) {
      a[2 * k]     = fmaf(v0, __uint_as_float(uu0[k] << 16),
                     fmaf(v1, __uint_as_float(uu1[k] << 16), a[2 * k]));
      a[2 * k + 1] = fmaf(v0, __uint_as_float(uu0[k] & 0xFFFF0000u),
                     fmaf(v1, __uint_as_float(uu1[k] & 0xFFFF0000u), a[2 * k + 1]));
      b[2 * k]     = fmaf(v0, __uint_as_float(ww0[k] << 16),
                     fmaf(v1, __uint_as_float(ww1[k] << 16), b[2 * k]));
      b[2 * k + 1] = fmaf(v0, __uint_as_float(ww0[k] & 0xFFFF0000u),
                     fmaf(v1, __uint_as_float(ww1[k] & 0xFFFF0000u), b[2 * k + 1]));
    }
  }
  if (j < e) {
    int c = ci[j];
    float v = cv[j];
    size_t off = (size_t)c * 64 + li * 4;
    uint4 u = *(const uint4*)(ga + off);
    uint4 w = *(const uint4*)(gb + off);
    unsigned int uu[4] = {u.x, u.y, u.z, u.w};
    unsigned int ww[4] = {w.x, w.y, w.z, w.w};
#pragma unroll
    for (int k = 0; k < 4; ++k) {
      a[2 * k]     = fmaf(v, __uint_as_float(uu[k] << 16), a[2 * k]);
      a[2 * k + 1] = fmaf(v, __uint_as_float(uu[k] & 0xFFFF0000u), a[2 * k + 1]);
      b[2 * k]     = fmaf(v, __uint_as_float(ww[k] << 16), b[2 * k]);
      b[2 * k + 1] = fmaf(v, __uint_as_float(ww[k] & 0xFFFF0000u), b[2 * k + 1]);
    }
  }
#pragma unroll
  for (int k = 0; k < 8; ++k) {
    a[k] += __shfl_xor(a[k], 16); a[k] += __shfl_xor(a[k], 32);
    b[k] += __shfl_xor(b[k], 16); b[k] += __shfl_xor(b[k], 32);
  }
  if (es == 0) {
    float ra = rsa[r], rb = rsb[r];
    size_t off = (size_t)r * 64 + li * 4;
    uint4 o;
    o.x = pk2(a[0] * ra, a[1] * ra); o.y = pk2(a[2] * ra, a[3] * ra);
    o.z = pk2(a[4] * ra, a[5] * ra); o.w = pk2(a[6] * ra, a[7] * ra);
    *(uint4*)(ya + off) = o;
    o.x = pk2(b[0] * rb, b[1] * rb); o.y = pk2(b[2] * rb, b[3] * rb);
    o.z = pk2(b[4] * rb, b[5] * rb); o.w = pk2(b[6] * rb, b[7] * rb);
    *(uint4*)(yb + off) = o;
  }
}

// ---------------- MFMA fused GEMM: out = 0.5*sum_i Yi@Wi + bias ----------------
// Prefetch ALL 24 A-fragments first (24 outstanding HBM loads/wave), then
// MFMA against L2-resident Wt.
struct Y6 { const unsigned short* y[6]; };

__global__ __launch_bounds__(128) void gemm6m_k(
    Y6 ys, const unsigned short* __restrict__ Wt, const float* __restrict__ bias,
    void* __restrict__ outp, int M, const int* flags) {
  int ff = flags[0];
  int wave = threadIdx.x >> 6;
  int lane = threadIdx.x & 63;
  int m = lane & 15, q = lane >> 4;
  int r0 = blockIdx.x * 32 + wave * 16;
  int rowA = r0 + m;
  bool okA = rowA < M;
  bf16x8 af[24];
#pragma unroll
  for (int seg = 0; seg < 6; ++seg) {
    const unsigned short* Y = ys.y[seg];
#pragma unroll
    for (int kc = 0; kc < 4; ++kc) {
      bf16x8 z = {0, 0, 0, 0, 0, 0, 0, 0};
      af[seg * 4 + kc] = okA ? *(const bf16x8*)(Y + (size_t)rowA * FD + kc * 32 + q * 8) : z;
    }
  }
  f32x4 acc[8];
#pragma unroll
  for (int nt = 0; nt < 8; ++nt) acc[nt] = (f32x4){0.f, 0.f, 0.f, 0.f};
#pragma unroll
  for (int i = 0; i < 24; ++i) {
#pragma unroll
    for (int nt = 0; nt < 8; ++nt) {
      bf16x8 bf = *(const bf16x8*)(Wt + (size_t)(nt * 16 + m) * 768 + i * 32 + q * 8);
      acc[nt] = __builtin_amdgcn_mfma_f32_16x16x32_bf16(af[i], bf, acc[nt], 0, 0, 0);
    }
  }
#pragma unroll
  for (int nt = 0; nt < 8; ++nt) {
    int col = nt * 16 + m;
    float bv = bias[col];
#pragma unroll
    for (int rg = 0; rg < 4; ++rg) {
      int grow = r0 + q * 4 + rg;
      if (grow >= M) continue;
      float v = 0.5f * acc[nt][rg] + bv;
      if (ff) ((float*)outp)[(size_t)grow * FD + col] = v;
      else ((unsigned short*)outp)[(size_t)grow * FD + col] =
          __bfloat16_as_ushort(__float2bfloat16(v));
    }
  }
}

// ---------------- legacy Path B kernels (proven round 4) ----------------
__global__ __launch_bounds__(128) void spmm_k(
    const int* __restrict__ rp, const void* __restrict__ ci, int cif,
    const void* __restrict__ cv, int cvf,
    const void* __restrict__ x, int xf, __hip_bfloat16* __restrict__ y,
    int n, int nnzMax,
    const float* __restrict__ cscale, const float* __restrict__ rscale,
    const int* flags) {
  int ff = flags[0], fi = flags[1];
  int vf = cvf ? 1 : ff;
  int iw = cif ? fi : 0;
  int xw = xf ? ff : 0;
  const int t = threadIdx.x;
  int r0 = blockIdx.x * 4;
  int rend = min(r0 + 4, n);
  for (int r = r0; r < rend; ++r) {
    int s = rp[r], e = rp[r + 1];
    s = max(0, min(s, nnzMax));
    e = max(s, min(e, nnzMax));
    float acc = 0.f;
    for (int j = s; j < e; ++j) {
      int c = ldi(ci, j, iw);
      if ((unsigned)c >= (unsigned)n) c = 0;
      float v = (vf ? ((const float*)cv)[j] : b2f(((const __hip_bfloat16*)cv)[j]));
      if (cscale) v *= cscale[c];
      float xv = xw ? ((const float*)x)[c * FD + t]
                    : b2f(((const __hip_bfloat16*)x)[c * FD + t]);
      acc = fmaf(v, xv, acc);
    }
    if (rscale) acc *= rscale[r];
    y[r * FD + t] = __float2bfloat16(acc);
  }
}

__global__ __launch_bounds__(256) void gemm_k(
    const __hip_bfloat16* __restrict__ Y, const void* __restrict__ W,
    const float* __restrict__ bias, const void* __restrict__ accin,
    void* __restrict__ outp, int M, const int* flags) {
  int ff = flags[0];
  __shared__ __align__(16) float Wl[32 * 128];
  __shared__ __align__(16) float Yl[64 * 36];
  const int t = threadIdx.x;
  const int row0 = blockIdx.x * 64;
  const int c4 = (t & 31) * 4;
  const int r8 = (t >> 5) * 8;
  const int rs = t >> 3;
  const int q = t & 7;
  float acc[8][4];
#pragma unroll
  for (int m = 0; m < 8; ++m)
#pragma unroll
    for (int j = 0; j < 4; ++j) acc[m][j] = 0.f;
  for (int kc = 0; kc < 4; ++kc) {
    if (ff) {
      const float4* Wg4 = (const float4*)((const float*)W + kc * 32 * 128);
#pragma unroll
      for (int i = 0; i < 4; ++i)
        *(float4*)(Wl + (t + i * 256) * 4) = Wg4[t + i * 256];
    } else {
      const ushort4* Wg4 = (const ushort4*)((const unsigned short*)W + kc * 32 * 128);
#pragma unroll
      for (int i = 0; i < 4; ++i) {
        ushort4 u = Wg4[t + i * 256];
        int base = (t + i * 256) * 4;
        Wl[base + 0] = bfu2f(u.x);
        Wl[base + 1] = bfu2f(u.y);
        Wl[base + 2] = bfu2f(u.z);
        Wl[base + 3] = bfu2f(u.w);
      }
    }
#pragma unroll
    for (int i = 0; i < 2; ++i) {
      int rr = rs + i * 32;
      int grow = row0 + rr;
      ushort4 u = make_ushort4(0, 0, 0, 0);
      if (grow < M)
        u = *(const ushort4*)((const unsigned short*)Y + grow * FD + kc * 32 + q * 4);
      float* yd = Yl + rr * 36 + q * 4;
      yd[0] = bfu2f(u.x); yd[1] = bfu2f(u.y); yd[2] = bfu2f(u.z); yd[3] = bfu2f(u.w);
    }
    __syncthreads();
#pragma unroll
    for (int kk = 0; kk < 32; kk += 4) {
      float4 w0 = *(const float4*)(Wl + (kk + 0) * 128 + c4);
      float4 w1 = *(const float4*)(Wl + (kk + 1) * 128 + c4);
      float4 w2 = *(const float4*)(Wl + (kk + 2) * 128 + c4);
      float4 w3 = *(const float4*)(Wl + (kk + 3) * 128 + c4);
#pragma unroll
      for (int m = 0; m < 8; ++m) {
        float4 yv = *(const float4*)(Yl + (r8 + m) * 36 + kk);
        acc[m][0] = fmaf(yv.x, w0.x, acc[m][0]);
        acc[m][1] = fmaf(yv.x, w0.y, acc[m][1]);
        acc[m][2] = fmaf(yv.x, w0.z, acc[m][2]);
        acc[m][3] = fmaf(yv.x, w0.w, acc[m][3]);
        acc[m][0] = fmaf(yv.y, w1.x, acc[m][0]);
        acc[m][1] = fmaf(yv.y, w1.y, acc[m][1]);
        acc[m][2] = fmaf(yv.y, w1.z, acc[m][2]);
        acc[m][3] = fmaf(yv.y, w1.w, acc[m][3]);
        acc[m][0] = fmaf(yv.z, w2.x, acc[m][0]);
        acc[m][1] = fmaf(yv.z, w2.y, acc[m][1]);
        acc[m][2] = fmaf(yv.z, w2.z, acc[m][2]);
        acc[m][3] = fmaf(yv.z, w2.w, acc[m][3]);
        acc[m][0] = fmaf(yv.w, w3.x, acc[m][0]);
        acc[m][1] = fmaf(yv.w, w3.y, acc[m][1]);
        acc[m][2] = fmaf(yv.w, w3.z, acc[m][2]);
        acc[m][3] = fmaf(yv.w, w3.w, acc[m][3]);
      }
    }
    __syncthreads();
  }
  float4 b4 = make_float4(0.f, 0.f, 0.f, 0.f);
  if (bias) b4 = *(const float4*)(bias + c4);
#pragma unroll
  for (int m = 0; m < 8; ++m) {
    int grow = row0 + r8 + m;
    if (grow >= M) continue;
    float4 rv;
    rv.x = 0.5f * acc[m][0] + b4.x;
    rv.y = 0.5f * acc[m][1] + b4.y;
    rv.z = 0.5f * acc[m][2] + b4.z;
    rv.w = 0.5f * acc[m][3] + b4.w;
    if (accin) {
      if (ff) {
        float4 o = *(const float4*)((const float*)accin + grow * FD + c4);
        rv.x += o.x; rv.y += o.y; rv.z += o.z; rv.w += o.w;
      } else {
        ushort4 o = *(const ushort4*)((const unsigned short*)accin + grow * FD + c4);
        rv.x += bfu2f(o.x); rv.y += bfu2f(o.y); rv.z += bfu2f(o.z); rv.w += bfu2f(o.w);
      }
    }
    if (ff) {
      *(float4*)((float*)outp + grow * FD + c4) = rv;
    } else {
      ushort4 so;
      so.x = __bfloat16_as_ushort(__float2bfloat16(rv.x));
      so.y = __bfloat16_as_ushort(__float2bfloat16(rv.y));
      so.z = __bfloat16_as_ushort(__float2bfloat16(rv.z));
      so.w = __bfloat16_as_ushort(__float2bfloat16(rv.w));
      *(ushort4*)((unsigned short*)outp + grow * FD + c4) = so;
    }
  }
}

extern "C" void kernel_launch(void* const* d_in, const int* in_sizes, int n_in,
                              void* d_out, int out_size, void* d_ws, size_t ws_size,
                              hipStream_t stream) {
  const void* x    = d_in[0];
  const void* w_sd = d_in[1];
  const void* b_sd = d_in[2];
  const void* w_ds = d_in[3];
  const void* b_ds = d_in[4];
  const void* w0   = d_in[5];
  const void* b0   = d_in[6];
  const void* w1   = d_in[7];
  const void* b1   = d_in[8];
  const void* w2   = d_in[9];
  const void* b2   = d_in[10];
  const void* w3   = d_in[11];
  const void* b3   = d_in[12];
  const void* a_rows = d_in[13];
  const void* a_cols = d_in[14];
  const void* a_vals = d_in[15];
  const int nnz = in_sizes[13];
  const int N = in_sizes[0] / FD;

  const size_t BUF = ((size_t)N * FD * 2 + 255) & ~(size_t)255;

  auto misc_need = [&](int nbig) -> size_t {
    size_t need = (size_t)nbig * BUF;
    need += ((size_t)10 * N * 4 + 255) & ~(size_t)255;          // degf
    need += 512 + 256 + 1024;                                    // biasf, flags, bsum
    need += (((size_t)(N + 1) * 4 + 255) & ~(size_t)255) * 2;   // rpA, rpT
    need += (((size_t)N * 4 + 255) & ~(size_t)255) * 2;         // curT, cntT
    need += (((size_t)nnz * 4 + 255) & ~(size_t)255) * 5;       // tSrc,tValF,aRow32,aCol32,aValF
    need += (6 * 16384 * 2 + 255) & ~(size_t)255;               // Wt
    return need;
  };
  size_t needA = misc_need(8);
  size_t needB = misc_need(2);

  int pathA = (ws_size >= needA) ? 1 : 0;
  if (!pathA && ws_size < needB) {
    fill_k<<<(out_size + 255) / 256, 256, 0, stream>>>((unsigned short*)d_out, out_size);
    return;
  }

  int nbig = pathA ? 8 : 2;
  char* p = (char*)d_ws;
  char* bufs[8];
  for (int i = 0; i < 8; ++i) bufs[i] = (i < nbig) ? (p + (size_t)i * BUF) : nullptr;
  char* q = p + (size_t)nbig * BUF;
  auto take = [&](size_t bytes) -> char* {
    char* r = q;
    q += (bytes + 255) & ~(size_t)255;
    return r;
  };
  float* degf  = (float*)take((size_t)10 * N * 4);
  float* biasf = (float*)take(512);
  int*   flags = (int*)take(256);
  int*   bsum  = (int*)take(1024);
  int* rpA  = (int*)take((size_t)(N + 1) * 4);
  int* rpT  = (int*)take((size_t)(N + 1) * 4);
  int* curT = (int*)take((size_t)N * 4);
  int* cntT = (int*)take((size_t)N * 4);
  int* tSrc = (int*)take((size_t)nnz * 4);
  float* tValF = (float*)take((size_t)nnz * 4);
  int* aRow32 = (int*)take((size_t)nnz * 4);
  int* aCol32 = (int*)take((size_t)nnz * 4);
  float* aValF = (float*)take((size_t)nnz * 4);
  __hip_bfloat16* Wt = (__hip_bfloat16*)take(6 * 16384 * 2);

  float* u1 = degf;
  float* v1 = degf + N;
  float* e1 = degf + 2 * N;
  float* s1 = degf + 6 * N;
  float* s2 = degf + 7 * N;
  float* s3 = degf + 8 * N;
  float* s4 = degf + 9 * N;

  int eb = (nnz + 255) / 256;
  int nb = (N + 255) / 256;

  detect_k<<<1, 256, 0, stream>>>(x, a_cols, flags);
  cvtall_k<<<eb, 256, 0, stream>>>(a_rows, a_cols, a_vals, nnz, N, aRow32, aCol32, aValF, flags);
  hipMemsetAsync(degf, 0, (size_t)6 * N * 4, stream);
  hipMemsetAsync(cntT, 0, (size_t)N * 4, stream);
  hist_k<<<eb, 256, 0, stream>>>(aRow32, aCol32, aValF, nnz, u1, v1, cntT);
  scanA_k<<<nb, 256, 0, stream>>>(cntT, N, bsum);
  scanB_k<<<1, 256, 0, stream>>>(bsum, nb, rpT + N);
  scanC_k<<<nb, 256, 0, stream>>>(cntT, N, bsum, rpT, curT);
  bsearch_k<<<(N + 256) / 256, 256, 0, stream>>>(aRow32, nnz, N, rpA);
  scatter_k<<<eb, 256, 0, stream>>>(aRow32, aCol32, aValF, nnz, curT, tSrc, tValF);
  deg2_k<<<eb, 256, 0, stream>>>(aRow32, aCol32, aValF, nnz, u1, v1,
                                 e1, degf + 3 * N, degf + 4 * N, degf + 5 * N);
  rsqrt_k<<<(4 * N + 255) / 256, 256, 0, stream>>>(e1, s1, 4 * N);
  bias_k<<<1, FD, 0, stream>>>(b_sd, b_ds, b0, b1, b2, b3, biasf, flags);

  int sg2 = (N + 3) / 4;
  int gg = (N + 63) / 64;
  int gg2 = (N + 31) / 32;

  if (pathA) {
    W6p wargs;
    wargs.w[0] = w_sd; wargs.w[1] = w_ds; wargs.w[2] = w0;
    wargs.w[3] = w1;   wargs.w[4] = w2;   wargs.w[5] = w3;
    wt_k<<<(6 * 16384 + 255) / 256, 256, 0, stream>>>(wargs, Wt, flags);

    __hip_bfloat16* xb = (__hip_bfloat16*)bufs[0];
    cvtx_k<<<(N * FD / 4 + 255) / 256, 256, 0, stream>>>(x, xb, N * FD, flags);

    // prescaled per-edge values live in bufs[7] (dead until sh2 writes y3)
    float* vaT = (float*)bufs[7];
    float* vbT = vaT + nnz;
    float* vaA = vbT + nnz;
    float* vbA = vaA + nnz;
    prescale_k<<<eb, 256, 0, stream>>>(tSrc, tValF, aCol32, aValF,
                                       s1, s2, s3, s4, vaT, vbT, vaA, vbA, nnz);

    unsigned int* xbu = (unsigned int*)bufs[0];
    unsigned int* t2 = (unsigned int*)bufs[1];
    unsigned int* g3 = (unsigned int*)bufs[2];
    unsigned int* g6 = (unsigned int*)bufs[3];
    unsigned int* t1 = (unsigned int*)bufs[4];
    unsigned int* g4 = (unsigned int*)bufs[5];
    unsigned int* g5 = (unsigned int*)bufs[6];
    unsigned int* y3 = (unsigned int*)bufs[7];  // overwrites prescale arrays (dead)
    unsigned int* y5 = (unsigned int*)bufs[0];  // xb dead after first hops
    unsigned int* y4 = (unsigned int*)bufs[2];  // g3 dead after sh2#1
    unsigned int* y6 = (unsigned int*)bufs[6];  // g5 dead after sh2#1

    fh3_k<<<sg2, 256, 0, stream>>>(rpT, tSrc, tValF, vaT, vbT, xbu, t2, g3, g6, N);
    fh3_k<<<sg2, 256, 0, stream>>>(rpA, aCol32, aValF, vaA, vbA, xbu, t1, g4, g5, N);
    sh2_k<<<sg2, 256, 0, stream>>>(rpA, aCol32, aValF, g3, g5, y3, y5, s1, s3, N);
    sh2_k<<<sg2, 256, 0, stream>>>(rpT, tSrc, tValF, g4, g6, y4, y6, s2, s4, N);

    Y6 yargs;
    yargs.y[0] = (const unsigned short*)t1;
    yargs.y[1] = (const unsigned short*)t2;
    yargs.y[2] = (const unsigned short*)y3;
    yargs.y[3] = (const unsigned short*)y4;
    yargs.y[4] = (const unsigned short*)y5;
    yargs.y[5] = (const unsigned short*)y6;
    gemm6m_k<<<gg2, 128, 0, stream>>>(yargs, (const unsigned short*)Wt, biasf, d_out, N, flags);
  } else {
    __hip_bfloat16* Yb = (__hip_bfloat16*)bufs[0];
    __hip_bfloat16* gb = (__hip_bfloat16*)bufs[1];
    spmm_k<<<sg2, 128, 0, stream>>>(rpA, a_cols, 1, a_vals, 0, x, 1, Yb, N, nnz, nullptr, nullptr, flags);
    gemm_k<<<gg, 256, 0, stream>>>(Yb, w_sd, biasf, nullptr, d_out, N, flags);
    spmm_k<<<sg2, 128, 0, stream>>>(rpT, tSrc, 0, tValF, 1, x, 1, Yb, N, nnz, nullptr, nullptr, flags);
    gemm_k<<<gg, 256, 0, stream>>>(Yb, w_ds, nullptr, d_out, d_out, N, flags);
    spmm_k<<<sg2, 128, 0, stream>>>(rpT, tSrc, 0, tValF, 1, x, 1, gb, N, nnz, s1, nullptr, flags);
    spmm_k<<<sg2, 128, 0, stream>>>(rpA, a_cols, 1, a_vals, 0, gb, 0, Yb, N, nnz, nullptr, s1, flags);
    gemm_k<<<gg, 256, 0, stream>>>(Yb, w0, nullptr, d_out, d_out, N, flags);
    spmm_k<<<sg2, 128, 0, stream>>>(rpA, a_cols, 1, a_vals, 0, x, 1, gb, N, nnz, s2, nullptr, flags);
    spmm_k<<<sg2, 128, 0, stream>>>(rpT, tSrc, 0, tValF, 1, gb, 0, Yb, N, nnz, nullptr, s2, flags);
    gemm_k<<<gg, 256, 0, stream>>>(Yb, w1, nullptr, d_out, d_out, N, flags);
    spmm_k<<<sg2, 128, 0, stream>>>(rpA, a_cols, 1, a_vals, 0, x, 1, gb, N, nnz, s4, nullptr, flags);
    spmm_k<<<sg2, 128, 0, stream>>>(rpA, a_cols, 1, a_vals, 0, gb, 0, Yb, N, nnz, nullptr, s3, flags);
    gemm_k<<<gg, 256, 0, stream>>>(Yb, w2, nullptr, d_out, d_out, N, flags);
    spmm_k<<<sg2, 128, 0, stream>>>(rpT, tSrc, 0, tValF, 1, x, 1, gb, N, nnz, s3, nullptr, flags);
    spmm_k<<<sg2, 128, 0, stream>>>(rpT, tSrc, 0, tValF, 1, gb, 0, Yb, N, nnz, nullptr, s4, flags);
    gemm_k<<<gg, 256, 0, stream>>>(Yb, w3, nullptr, d_out, d_out, N, flags);
  }
}